// Round 3
// baseline (266.211 us; speedup 1.0000x reference)
//
#include <hip/hip_runtime.h>

// B=32, H=W=128, C_IN=C_OUT=32, 3x3 SAME conv, per-sample hypernet weights
// Wk[b] = (P[b] @ dense_w).reshape(3,3,32,32).
//
// Implicit GEMM per image: Y[p,co] = sum_k Xpatch[p,k]*W[k,co]; M=16384,N=32,K=288.
// K-chunk kc (32 wide) == tap (kh,kw)=(kc/3,kc%3), chunk-local k == ci.
// 16x16x32 f16 MFMA, A-frag A[m=lane&15][k=(lane>>4)*8+j] = 8 consecutive ci of
// one pixel = two float4 loads from X.

#define BATCH 32
#define HDIM 128
#define WDIM 128
#define CIN 32
#define COUT 32
#define PDIM 128
#define KCOLS 9216  // 3*3*32*32

typedef _Float16 f16x8 __attribute__((ext_vector_type(8)));
typedef float f32x4 __attribute__((ext_vector_type(4)));

// ---------------------------------------------------------------------------
// Kernel A: A = P @ dense_w (32x128 @ 128x9216) -> f16, swizzled to MFMA
// B-fragment layout WB[b][kc][ct][lane][j8], lane=(ci>>3)*16+(co&15), j8=ci&7,
// ct=co>>4.  v3: thread = (one col, one batch). Grid 1152 = 144 colgroups x
// 8 batchgroups -> 4.5 blocks/CU, 18 waves/CU (v2 had 1.1 blocks/CU: latency-
// bound at ~100us). Dw loads coalesced (lane = col); P rows in LDS, read at a
// wave-uniform address (broadcast, conflict-free). Dw streamed 8x at TCC level
// (37 MB) but 7/8 are L3 hits.
// ---------------------------------------------------------------------------
__global__ __launch_bounds__(256) void hyper_gemm(const float* __restrict__ P,
                                                  const float* __restrict__ Dw,
                                                  unsigned short* __restrict__ WB) {
    __shared__ float Pl[4 * PDIM];  // 2 KB: this block's 4 batches
    const int tid = threadIdx.x;
    const int cg = blockIdx.x % 144;  // 64-column group
    const int bg = blockIdx.x / 144;  // 0..7 -> batches bg*4..bg*4+3

    Pl[tid] = P[bg * 4 * PDIM + tid];
    Pl[tid + 256] = P[bg * 4 * PDIM + 256 + tid];
    __syncthreads();

    const int lane = tid & 63;
    const int wv = tid >> 6;  // batch sub-index 0..3
    const int col = cg * 64 + lane;
    const float* pw = &Pl[wv * PDIM];  // wave-uniform base

    float acc = 0.f;
#pragma unroll 8
    for (int m = 0; m < PDIM; ++m) {
        acc += Dw[m * KCOLS + col] * pw[m];  // load coalesced; pw[m] broadcast
    }

    // col = (tap*32 + ci)*32 + co  ->  swizzled B-fragment address
    const int k = col >> 5;
    const int co = col & 31;
    const int kc = k >> 5;
    const int ci = k & 31;
    const int base = ((kc * 2 + (co >> 4)) * 64 + (ci >> 3) * 16 + (co & 15)) * 8 + (ci & 7);
    const int b = bg * 4 + wv;
    _Float16 v = (_Float16)acc;
    WB[(size_t)b * KCOLS + base] = __builtin_bit_cast(unsigned short, v);
}

// ---------------------------------------------------------------------------
// Kernel B: implicit-GEMM conv. Grid 2048, 256 thr = 4 waves.
// Block = 4 rows x 64 cols of one image (X redundancy 1.55x, same as R1's
// best-traffic shape); wave = one row-half (4 tiles of 16 px).
// XCD swizzle: hw maps blockIdx%8 -> XCD round-robin, so we assign images
// 4*xcd..4*xcd+3 to XCD xcd: every block sharing an X row (and the per-image
// 18KB WB table) lands on the SAME XCD's L2 -> row overlap and WB re-stages
// are L2 hits, not HBM refetches (R2: 277MB fetch from cross-XCD duplication).
// B-frags staged in LDS (18KB); launch_bounds(256,8) -> 8 blocks/CU, 100% occ.
// ---------------------------------------------------------------------------
__global__ __launch_bounds__(256, 8) void cond_conv(const float* __restrict__ X,
                                                    const unsigned short* __restrict__ WB,
                                                    float* __restrict__ Y) {
    __shared__ unsigned short WBl[KCOLS];  // 18432 B
    const int tid = threadIdx.x;
    const int bid = blockIdx.x;
    const int xcd = bid & 7;
    const int n = bid >> 3;            // 0..255 within this XCD
    const int b = xcd * 4 + (n >> 6);  // image
    const int rem = n & 63;
    const int hg = rem >> 1;  // 4-row group 0..31
    const int wh = rem & 1;   // row half 0/1

    // stage the whole per-image fragment table (16B chunks, coalesced)
    {
        const uint4* src = (const uint4*)(WB + (size_t)b * KCOLS);
        uint4* dst = (uint4*)WBl;
        for (int i = tid; i < KCOLS / 8; i += 256) dst[i] = src[i];
    }
    __syncthreads();

    const int wave = tid >> 6;
    const int lane = tid & 63;
    const int h = hg * 4 + wave;
    const int wbase = wh * 64;
    const int quad = lane >> 4;
    const int m16 = lane & 15;

    const f32x4* X4 = (const f32x4*)X;

    for (int t = 0; t < 4; ++t) {
        const int w0 = wbase + t * 16;
        f32x4 acc0 = {0.f, 0.f, 0.f, 0.f};
        f32x4 acc1 = {0.f, 0.f, 0.f, 0.f};
#pragma unroll
        for (int kc = 0; kc < 9; ++kc) {
            const int kh = kc / 3, kw = kc % 3;
            const int hh = h + kh - 1;         // wave-uniform
            const int ww = w0 + m16 + kw - 1;  // per-lane
            const bool ok = (hh >= 0) & (hh < HDIM) & (ww >= 0) & (ww < WDIM);
            int idx = ((b * HDIM + hh) * WDIM + ww) * 8 + quad * 2;  // float4 units
            idx = ok ? idx : 0;
            f32x4 lo = X4[idx];
            f32x4 hi = X4[idx + 1];
            if (!ok) { lo = (f32x4)(0.f); hi = (f32x4)(0.f); }
            f16x8 a;
#pragma unroll
            for (int j = 0; j < 4; ++j) {
                a[j] = (_Float16)lo[j];
                a[4 + j] = (_Float16)hi[j];
            }
            const f16x8 bf0 = *(const f16x8*)(WBl + ((kc * 2 + 0) * 64 + lane) * 8);
            const f16x8 bf1 = *(const f16x8*)(WBl + ((kc * 2 + 1) * 64 + lane) * 8);
            acc0 = __builtin_amdgcn_mfma_f32_16x16x32_f16(a, bf0, acc0, 0, 0, 0);
            acc1 = __builtin_amdgcn_mfma_f32_16x16x32_f16(a, bf1, acc1, 0, 0, 0);
        }
        // D layout: col = lane&15 (co), row = quad*4 + r (pixel); acc0/acc1
        // together complete each 128B Y line (one pixel's 32 co).
        float* yp = Y + (((size_t)(b * HDIM + h) * WDIM) + w0 + quad * 4) * COUT + m16;
#pragma unroll
        for (int r = 0; r < 4; ++r) {
            yp[r * COUT] = acc0[r];
            yp[r * COUT + 16] = acc1[r];
        }
    }
}

extern "C" void kernel_launch(void* const* d_in, const int* in_sizes, int n_in,
                              void* d_out, int out_size, void* d_ws, size_t ws_size,
                              hipStream_t stream) {
    const float* X = (const float*)d_in[0];   // [32,128,128,32]
    const float* P = (const float*)d_in[1];   // [32,128]
    const float* Dw = (const float*)d_in[2];  // [128,9216]
    float* Y = (float*)d_out;                 // [32,128,128,32]
    unsigned short* WB = (unsigned short*)d_ws;  // 32*9216 f16 = 576 KiB

    hipLaunchKernelGGL(hyper_gemm, dim3(1152), dim3(256), 0, stream, P, Dw, WB);
    hipLaunchKernelGGL(cond_conv, dim3(2048), dim3(256), 0, stream, X, WB, Y);
}

// Round 4
// 184.285 us; speedup vs baseline: 1.4446x; 1.4446x over previous
//
#include <hip/hip_runtime.h>

// B=32, H=W=128, C_IN=C_OUT=32, 3x3 SAME conv, per-sample hypernet weights
// Wk[b] = (P[b] @ dense_w).reshape(3,3,32,32).
//
// Implicit GEMM per image: Y[p,co] = sum_k Xpatch[p,k]*W[k,co]; M=16384,N=32,K=288.
// K-chunk kc (32 wide) == tap (kh,kw)=(kc/3,kc%3), chunk-local k == ci.
// 16x16x32 f16 MFMA; A-frag A[m=lane&15][k=(lane>>4)*8+j] = 8 consecutive ci of
// one pixel = two float4 loads from X.
//
// GEOMETRY NOTE (empirical, R1-R3): block = 4 rows x FULL width, grid 1024
// (4 blocks/CU) measured FETCH 51MB / WRITE 65.5MB (ideal). Narrower or
// shorter blocks at 8 blocks/CU measured 235-277MB FETCH / 148MB WRITE.
// Do not shrink blocks or raise blocks/CU past 4.

#define BATCH 32
#define HDIM 128
#define WDIM 128
#define CIN 32
#define COUT 32
#define PDIM 128
#define KCOLS 9216  // 3*3*32*32

typedef _Float16 f16x8 __attribute__((ext_vector_type(8)));
typedef float f32x4 __attribute__((ext_vector_type(4)));

// ---------------------------------------------------------------------------
// Kernel A: A = P @ dense_w (32x128 @ 128x9216) -> f16, swizzled to MFMA
// B-fragment layout WB[b][kc][ct][lane][j8], lane=(ci>>3)*16+(co&15), j8=ci&7,
// ct=co>>4. Grid 1152 = 144 colgroups x 8 batchgroups (4.5 blocks/CU).
// Dw loads coalesced (lane = col); P rows in LDS read wave-uniform (broadcast).
// ---------------------------------------------------------------------------
__global__ __launch_bounds__(256) void hyper_gemm(const float* __restrict__ P,
                                                  const float* __restrict__ Dw,
                                                  unsigned short* __restrict__ WB) {
    __shared__ float Pl[4 * PDIM];  // 2 KB: this block's 4 batches
    const int tid = threadIdx.x;
    const int cg = blockIdx.x % 144;  // 64-column group
    const int bg = blockIdx.x / 144;  // 0..7 -> batches bg*4..bg*4+3

    Pl[tid] = P[bg * 4 * PDIM + tid];
    Pl[tid + 256] = P[bg * 4 * PDIM + 256 + tid];
    __syncthreads();

    const int lane = tid & 63;
    const int wv = tid >> 6;  // batch sub-index 0..3
    const int col = cg * 64 + lane;
    const float* pw = &Pl[wv * PDIM];  // wave-uniform base

    float acc = 0.f;
#pragma unroll 8
    for (int m = 0; m < PDIM; ++m) {
        acc += Dw[m * KCOLS + col] * pw[m];  // load coalesced; pw[m] broadcast
    }

    const int k = col >> 5;
    const int co = col & 31;
    const int kc = k >> 5;
    const int ci = k & 31;
    const int base = ((kc * 2 + (co >> 4)) * 64 + (ci >> 3) * 16 + (co & 15)) * 8 + (ci & 7);
    const int b = bg * 4 + wv;
    _Float16 v = (_Float16)acc;
    WB[(size_t)b * KCOLS + base] = __builtin_bit_cast(unsigned short, v);
}

// ---------------------------------------------------------------------------
// Kernel B: implicit-GEMM conv. R1 geometry (traffic-optimal, see note above):
// grid 1024 = 32 b x 32 rowgroups, 4 waves, wave = one full row, 8 tiles of
// 16 px. R2's LDS frag staging (kills R1's per-tile global frag reloads that
// made it latency-bound at 1.36TB/s). Two-phase tile body: all 18 X loads
// issued before any cvt/MFMA (18KB/wave in flight); unroll 2 overlaps tiles.
// Y stores nontemporal: write-once data, keep out of L2, full 64B sectors.
// ---------------------------------------------------------------------------
__global__ __launch_bounds__(256, 4) void cond_conv(const float* __restrict__ X,
                                                    const unsigned short* __restrict__ WB,
                                                    float* __restrict__ Y) {
    __shared__ unsigned short WBl[KCOLS];  // 18432 B -> LDS caps at 8 blk/CU; grid gives 4
    const int tid = threadIdx.x;
    const int b = blockIdx.x >> 5;
    const int hg = blockIdx.x & 31;

    // stage the per-image fragment table (16B chunks, coalesced)
    {
        const uint4* src = (const uint4*)(WB + (size_t)b * KCOLS);
        uint4* dst = (uint4*)WBl;
        for (int i = tid; i < KCOLS / 8; i += 256) dst[i] = src[i];
    }
    __syncthreads();

    const int wave = tid >> 6;
    const int lane = tid & 63;
    const int h = hg * 4 + wave;
    const int quad = lane >> 4;
    const int m16 = lane & 15;

    const f32x4* X4 = (const f32x4*)X;

#pragma unroll 2
    for (int t = 0; t < 8; ++t) {
        const int w0 = t * 16;

        // Phase 1: issue all 18 independent global loads for this tile.
        f32x4 xlo[9], xhi[9];
#pragma unroll
        for (int kc = 0; kc < 9; ++kc) {
            const int kh = kc / 3, kw = kc % 3;
            const int hh = h + kh - 1;         // wave-uniform
            const int ww = w0 + m16 + kw - 1;  // per-lane
            const bool ok = (hh >= 0) & (hh < HDIM) & (ww >= 0) & (ww < WDIM);
            int idx = ((b * HDIM + hh) * WDIM + ww) * 8 + quad * 2;  // float4 units
            idx = ok ? idx : 0;
            f32x4 lo = X4[idx];
            f32x4 hi = X4[idx + 1];
            if (!ok) { lo = (f32x4)(0.f); hi = (f32x4)(0.f); }
            xlo[kc] = lo;
            xhi[kc] = hi;
        }

        // Phase 2: cvt + MFMA (B-frags from LDS; ds_read latency hidden under
        // the global loads above).
        f32x4 acc0 = {0.f, 0.f, 0.f, 0.f};
        f32x4 acc1 = {0.f, 0.f, 0.f, 0.f};
#pragma unroll
        for (int kc = 0; kc < 9; ++kc) {
            f16x8 a;
#pragma unroll
            for (int j = 0; j < 4; ++j) {
                a[j] = (_Float16)xlo[kc][j];
                a[4 + j] = (_Float16)xhi[kc][j];
            }
            const f16x8 bf0 = *(const f16x8*)(WBl + ((kc * 2 + 0) * 64 + lane) * 8);
            const f16x8 bf1 = *(const f16x8*)(WBl + ((kc * 2 + 1) * 64 + lane) * 8);
            acc0 = __builtin_amdgcn_mfma_f32_16x16x32_f16(a, bf0, acc0, 0, 0, 0);
            acc1 = __builtin_amdgcn_mfma_f32_16x16x32_f16(a, bf1, acc1, 0, 0, 0);
        }

        // D layout: col = lane&15 (co), row = quad*4 + r (pixel). acc0+acc1
        // stores are the two 64B sectors of each pixel's 128B line.
        float* yp = Y + (((size_t)(b * HDIM + h) * WDIM) + w0 + quad * 4) * COUT + m16;
#pragma unroll
        for (int r = 0; r < 4; ++r) {
            __builtin_nontemporal_store(acc0[r], yp + r * COUT);
            __builtin_nontemporal_store(acc1[r], yp + r * COUT + 16);
        }
    }
}

extern "C" void kernel_launch(void* const* d_in, const int* in_sizes, int n_in,
                              void* d_out, int out_size, void* d_ws, size_t ws_size,
                              hipStream_t stream) {
    const float* X = (const float*)d_in[0];   // [32,128,128,32]
    const float* P = (const float*)d_in[1];   // [32,128]
    const float* Dw = (const float*)d_in[2];  // [128,9216]
    float* Y = (float*)d_out;                 // [32,128,128,32]
    unsigned short* WB = (unsigned short*)d_ws;  // 32*9216 f16 = 576 KiB

    hipLaunchKernelGGL(hyper_gemm, dim3(1152), dim3(256), 0, stream, P, Dw, WB);
    hipLaunchKernelGGL(cond_conv, dim3(1024), dim3(256), 0, stream, X, WB, Y);
}

// Round 5
// 169.730 us; speedup vs baseline: 1.5684x; 1.0858x over previous
//
#include <hip/hip_runtime.h>

// B=32, H=W=128, C_IN=C_OUT=32, 3x3 SAME conv, per-sample hypernet weights
// Wk[b] = (P[b] @ dense_w).reshape(3,3,32,32).
//
// Implicit GEMM per image: Y[p,co] = sum_k Xpatch[p,k]*W[k,co]; M=16384,N=32,K=288.
// K-chunk kc (32 wide) == tap (kh,kw)=(kc/3,kc%3), chunk-local k == ci.
// 16x16x32 f16 MFMA; A-frag A[m=lane&15][k=(lane>>4)*8+j] = 8 consecutive ci
// of one pixel = ONE 16B load from pre-converted f16 X.
//
// GEOMETRY NOTE (empirical, R1-R4): block = 4 rows x FULL width, grid 1024
// (4 blocks/CU) measured FETCH 51MB / WRITE 66-71MB (ideal). Narrower blocks
// at 8 blocks/CU measured 235-277MB FETCH / 148MB WRITE. Keep this geometry.
//
// R4 lesson: VGPR=56 showed the compiler collapsed the "load all then compute"
// phases -> latency-bound at 1.38TB/s. R5: f16 X (halves VMEM count, kills
// in-loop cvt) + explicit next-tile prefetch with NO VALU consumer on the
// prefetched regs (masked lanes read a zeroed slot Xh8[-1], no cndmask).

#define BATCH 32
#define HDIM 128
#define WDIM 128
#define CIN 32
#define COUT 32
#define PDIM 128
#define KCOLS 9216  // 3*3*32*32
#define XELEMS (BATCH * HDIM * WDIM * CIN)  // 16,777,216

typedef _Float16 f16x8 __attribute__((ext_vector_type(8)));
typedef float f32x4 __attribute__((ext_vector_type(4)));

// ---------------------------------------------------------------------------
// Kernel A: A = P @ dense_w (32x128 @ 128x9216) -> f16, swizzled to MFMA
// B-fragment layout WB[b][kc][ct][lane][j8], lane=(ci>>3)*16+(co&15), j8=ci&7,
// ct=co>>4. Grid 1152 = 144 colgroups x 8 batchgroups (4.5 blocks/CU).
// ---------------------------------------------------------------------------
__global__ __launch_bounds__(256) void hyper_gemm(const float* __restrict__ P,
                                                  const float* __restrict__ Dw,
                                                  unsigned short* __restrict__ WB) {
    __shared__ float Pl[4 * PDIM];  // 2 KB: this block's 4 batches
    const int tid = threadIdx.x;
    const int cg = blockIdx.x % 144;  // 64-column group
    const int bg = blockIdx.x / 144;  // 0..7 -> batches bg*4..bg*4+3

    Pl[tid] = P[bg * 4 * PDIM + tid];
    Pl[tid + 256] = P[bg * 4 * PDIM + 256 + tid];
    __syncthreads();

    const int lane = tid & 63;
    const int wv = tid >> 6;  // batch sub-index 0..3
    const int col = cg * 64 + lane;
    const float* pw = &Pl[wv * PDIM];  // wave-uniform base

    float acc = 0.f;
#pragma unroll 8
    for (int m = 0; m < PDIM; ++m) {
        acc += Dw[m * KCOLS + col] * pw[m];  // load coalesced; pw[m] broadcast
    }

    const int k = col >> 5;
    const int co = col & 31;
    const int kc = k >> 5;
    const int ci = k & 31;
    const int base = ((kc * 2 + (co >> 4)) * 64 + (ci >> 3) * 16 + (co & 15)) * 8 + (ci & 7);
    const int b = bg * 4 + wv;
    _Float16 v = (_Float16)acc;
    WB[(size_t)b * KCOLS + base] = __builtin_bit_cast(unsigned short, v);
}

// ---------------------------------------------------------------------------
// x_cvt: X f32 -> f16, same NHWC layout. Also zeroes the 16B slot at Xh8[-1]
// used by cond_conv's masked (out-of-image) fragment loads.
// 2048 blocks x 256 thr, 4 chunks of 8 elems each: BW-bound.
// ---------------------------------------------------------------------------
__global__ __launch_bounds__(256) void x_cvt(const float* __restrict__ X,
                                             f16x8* __restrict__ Xh8) {
    const int i0 = blockIdx.x * 256 + threadIdx.x;
    if (i0 == 0) {
        f16x8 z;
#pragma unroll
        for (int j = 0; j < 8; ++j) z[j] = (_Float16)0.f;
        Xh8[-1] = z;  // zero pad slot for masked loads
    }
    const f32x4* X4 = (const f32x4*)X;
#pragma unroll
    for (int r = 0; r < 4; ++r) {
        const int c = i0 + r * 524288;  // chunk of 8 floats
        f32x4 a = X4[2 * c];
        f32x4 b = X4[2 * c + 1];
        f16x8 o;
#pragma unroll
        for (int j = 0; j < 4; ++j) {
            o[j] = (_Float16)a[j];
            o[4 + j] = (_Float16)b[j];
        }
        Xh8[c] = o;
    }
}

// ---------------------------------------------------------------------------
// Kernel B (f16 path): implicit-GEMM conv, software-pipelined.
// Grid 1024 = 32 b x 32 rowgroups, 4 waves; wave = one full row, 8 tiles of
// 16 px. Per tile: 9 A-frag loads (16B each, one per tap), 18 ds_read b-frags,
// 18 MFMA. Tile t+1's loads are issued before tile t's MFMAs; prefetched regs
// have no VALU consumer (masked lanes hit the zero slot) so no early waitcnt.
// ---------------------------------------------------------------------------
__device__ __forceinline__ void load_tile(const f16x8* __restrict__ Xh8, int b,
                                          int h, int w0, int quad, int m16,
                                          f16x8 buf[9]) {
#pragma unroll
    for (int kc = 0; kc < 9; ++kc) {
        const int kh = kc / 3, kw = kc % 3;
        const int hh = h + kh - 1;         // wave-uniform
        const int ww = w0 + m16 + kw - 1;  // per-lane
        const bool ok = (hh >= 0) & (hh < HDIM) & (ww >= 0) & (ww < WDIM);
        int idx = ((b * HDIM + hh) * WDIM + ww) * 4 + quad;  // 16B units
        idx = ok ? idx : -1;  // -1 -> zeroed pad slot
        buf[kc] = Xh8[idx];
    }
}

__global__ __launch_bounds__(256, 4) void cond_conv_f16(const f16x8* __restrict__ Xh8,
                                                        const unsigned short* __restrict__ WB,
                                                        float* __restrict__ Y) {
    __shared__ unsigned short WBl[KCOLS];  // 18432 B
    const int tid = threadIdx.x;
    const int b = blockIdx.x >> 5;
    const int hg = blockIdx.x & 31;

    // stage the per-image fragment table (16B chunks, coalesced)
    {
        const uint4* src = (const uint4*)(WB + (size_t)b * KCOLS);
        uint4* dst = (uint4*)WBl;
        for (int i = tid; i < KCOLS / 8; i += 256) dst[i] = src[i];
    }
    __syncthreads();

    const int wave = tid >> 6;
    const int lane = tid & 63;
    const int h = hg * 4 + wave;
    const int quad = lane >> 4;
    const int m16 = lane & 15;

    f16x8 cur[9], nxt[9];
    load_tile(Xh8, b, h, 0, quad, m16, cur);

#pragma unroll
    for (int t = 0; t < 8; ++t) {
        if (t < 7) load_tile(Xh8, b, h, (t + 1) * 16, quad, m16, nxt);

        f32x4 acc0 = {0.f, 0.f, 0.f, 0.f};
        f32x4 acc1 = {0.f, 0.f, 0.f, 0.f};
#pragma unroll
        for (int kc = 0; kc < 9; ++kc) {
            const f16x8 bf0 = *(const f16x8*)(WBl + ((kc * 2 + 0) * 64 + lane) * 8);
            const f16x8 bf1 = *(const f16x8*)(WBl + ((kc * 2 + 1) * 64 + lane) * 8);
            acc0 = __builtin_amdgcn_mfma_f32_16x16x32_f16(cur[kc], bf0, acc0, 0, 0, 0);
            acc1 = __builtin_amdgcn_mfma_f32_16x16x32_f16(cur[kc], bf1, acc1, 0, 0, 0);
        }

        // D layout: col = lane&15 (co), row = quad*4 + r (pixel). acc0+acc1
        // stores are the two 64B sectors of each pixel's 128B line.
        float* yp = Y + (((size_t)(b * HDIM + h) * WDIM) + t * 16 + quad * 4) * COUT + m16;
#pragma unroll
        for (int r = 0; r < 4; ++r) {
            __builtin_nontemporal_store(acc0[r], yp + r * COUT);
            __builtin_nontemporal_store(acc1[r], yp + r * COUT + 16);
        }

#pragma unroll
        for (int kc = 0; kc < 9; ++kc) cur[kc] = nxt[kc];  // renamed by unroll
    }
}

// ---------------------------------------------------------------------------
// Fallback (R4 path) if ws too small for Xh: f32 X, cvt in-kernel.
// ---------------------------------------------------------------------------
__global__ __launch_bounds__(256, 4) void cond_conv_f32(const float* __restrict__ X,
                                                        const unsigned short* __restrict__ WB,
                                                        float* __restrict__ Y) {
    __shared__ unsigned short WBl[KCOLS];
    const int tid = threadIdx.x;
    const int b = blockIdx.x >> 5;
    const int hg = blockIdx.x & 31;
    {
        const uint4* src = (const uint4*)(WB + (size_t)b * KCOLS);
        uint4* dst = (uint4*)WBl;
        for (int i = tid; i < KCOLS / 8; i += 256) dst[i] = src[i];
    }
    __syncthreads();

    const int wave = tid >> 6;
    const int lane = tid & 63;
    const int h = hg * 4 + wave;
    const int quad = lane >> 4;
    const int m16 = lane & 15;
    const f32x4* X4 = (const f32x4*)X;

#pragma unroll 2
    for (int t = 0; t < 8; ++t) {
        const int w0 = t * 16;
        f32x4 acc0 = {0.f, 0.f, 0.f, 0.f};
        f32x4 acc1 = {0.f, 0.f, 0.f, 0.f};
#pragma unroll
        for (int kc = 0; kc < 9; ++kc) {
            const int kh = kc / 3, kw = kc % 3;
            const int hh = h + kh - 1;
            const int ww = w0 + m16 + kw - 1;
            const bool ok = (hh >= 0) & (hh < HDIM) & (ww >= 0) & (ww < WDIM);
            int idx = ((b * HDIM + hh) * WDIM + ww) * 8 + quad * 2;
            idx = ok ? idx : 0;
            f32x4 lo = X4[idx];
            f32x4 hi = X4[idx + 1];
            if (!ok) { lo = (f32x4)(0.f); hi = (f32x4)(0.f); }
            f16x8 a;
#pragma unroll
            for (int j = 0; j < 4; ++j) {
                a[j] = (_Float16)lo[j];
                a[4 + j] = (_Float16)hi[j];
            }
            const f16x8 bf0 = *(const f16x8*)(WBl + ((kc * 2 + 0) * 64 + lane) * 8);
            const f16x8 bf1 = *(const f16x8*)(WBl + ((kc * 2 + 1) * 64 + lane) * 8);
            acc0 = __builtin_amdgcn_mfma_f32_16x16x32_f16(a, bf0, acc0, 0, 0, 0);
            acc1 = __builtin_amdgcn_mfma_f32_16x16x32_f16(a, bf1, acc1, 0, 0, 0);
        }
        float* yp = Y + (((size_t)(b * HDIM + h) * WDIM) + w0 + quad * 4) * COUT + m16;
#pragma unroll
        for (int r = 0; r < 4; ++r) {
            __builtin_nontemporal_store(acc0[r], yp + r * COUT);
            __builtin_nontemporal_store(acc1[r], yp + r * COUT + 16);
        }
    }
}

extern "C" void kernel_launch(void* const* d_in, const int* in_sizes, int n_in,
                              void* d_out, int out_size, void* d_ws, size_t ws_size,
                              hipStream_t stream) {
    const float* X = (const float*)d_in[0];   // [32,128,128,32]
    const float* P = (const float*)d_in[1];   // [32,128]
    const float* Dw = (const float*)d_in[2];  // [128,9216]
    float* Y = (float*)d_out;                 // [32,128,128,32]

    // ws layout: [WB: 589824 B][pad: 64 B, last 16 zeroed][Xh: 33.5 MB]
    unsigned short* WB = (unsigned short*)d_ws;
    const size_t need = (size_t)589824 + 64 + (size_t)XELEMS * 2;

    hipLaunchKernelGGL(hyper_gemm, dim3(1152), dim3(256), 0, stream, P, Dw, WB);

    if (ws_size >= need) {
        f16x8* Xh8 = (f16x8*)((char*)d_ws + 589824 + 64);
        hipLaunchKernelGGL(x_cvt, dim3(2048), dim3(256), 0, stream, X, Xh8);
        hipLaunchKernelGGL(cond_conv_f16, dim3(1024), dim3(256), 0, stream,
                           (const f16x8*)Xh8, WB, Y);
    } else {
        hipLaunchKernelGGL(cond_conv_f32, dim3(1024), dim3(256), 0, stream, X, WB, Y);
    }
}

// Round 6
// 147.297 us; speedup vs baseline: 1.8073x; 1.1523x over previous
//
#include <hip/hip_runtime.h>

// B=32, H=W=128, C_IN=C_OUT=32, 3x3 SAME conv, per-sample hypernet weights
// Wk[b] = (P[b] @ dense_w).reshape(3,3,32,32).
//
// Implicit GEMM per image: Y[p,co] = sum_k Xpatch[p,k]*W[k,co]; M=16384,N=32,K=288.
// K-chunk kc (32 wide) == tap (kh,kw)=(kc/3,kc%3), chunk-local k == ci.
// 16x16x32 f16 MFMA; A-frag A[m=lane&15][k=(lane>>4)*8+j] = 8 consecutive ci
// of one pixel = ONE 16B load from pre-converted f16 X.
//
// GEOMETRY NOTE (empirical, R1-R5): block = 4 rows x FULL width, grid 1024
// (4 blocks/CU). Narrower blocks at 8 blocks/CU exploded traffic 3x. Keep.
// R5 lesson: explicit next-tile prefetch (masked lanes -> zeroed pad slot, no
// cndmask consumer) got 3.65TB/s. R6: B-frags are tile-invariant -> hoist to
// VGPRs once (kills 18 ds_read_b128/tile = the largest per-tile issue cost);
// plain stores (nt defeated L2 half-line merge: WRITE 94MB vs 66 ideal);
// hyper_gemm + x_cvt fused into one launch (independent, overlap).

#define BATCH 32
#define HDIM 128
#define WDIM 128
#define CIN 32
#define COUT 32
#define PDIM 128
#define KCOLS 9216  // 3*3*32*32
#define XELEMS (BATCH * HDIM * WDIM * CIN)  // 16,777,216

typedef _Float16 f16x8 __attribute__((ext_vector_type(8)));
typedef float f32x4 __attribute__((ext_vector_type(4)));

// ---------------------------------------------------------------------------
// prep_fused: blocks [0,1152) = hyper GEMM (A = P @ dense_w -> f16, swizzled
// to MFMA B-frag layout WB[b][kc][ct][lane][j8]); blocks [1152,3200) =
// X f32->f16 cvt (+ zero pad slot). Independent work fused to overlap
// hyper's latency-bound loop under cvt's BW stream.
// ---------------------------------------------------------------------------
__global__ __launch_bounds__(256) void prep_fused(const float* __restrict__ P,
                                                  const float* __restrict__ Dw,
                                                  const float* __restrict__ X,
                                                  unsigned short* __restrict__ WB,
                                                  f16x8* __restrict__ Xh8) {
    __shared__ float Pl[4 * PDIM];  // 2 KB (hyper branch only)
    const int tid = threadIdx.x;

    if (blockIdx.x < 1152) {
        const int cg = blockIdx.x % 144;  // 64-column group
        const int bg = blockIdx.x / 144;  // batches bg*4..bg*4+3

        Pl[tid] = P[bg * 4 * PDIM + tid];
        Pl[tid + 256] = P[bg * 4 * PDIM + 256 + tid];
        __syncthreads();

        const int lane = tid & 63;
        const int wv = tid >> 6;
        const int col = cg * 64 + lane;
        const float* pw = &Pl[wv * PDIM];  // wave-uniform base

        float acc = 0.f;
#pragma unroll 8
        for (int m = 0; m < PDIM; ++m) {
            acc += Dw[m * KCOLS + col] * pw[m];  // coalesced; pw[m] broadcast
        }

        const int k = col >> 5;
        const int co = col & 31;
        const int kc = k >> 5;
        const int ci = k & 31;
        const int base =
            ((kc * 2 + (co >> 4)) * 64 + (ci >> 3) * 16 + (co & 15)) * 8 + (ci & 7);
        const int b = bg * 4 + wv;
        _Float16 v = (_Float16)acc;
        WB[(size_t)b * KCOLS + base] = __builtin_bit_cast(unsigned short, v);
    } else {
        const int i0 = (blockIdx.x - 1152) * 256 + tid;
        if (i0 == 0) {
            f16x8 z;
#pragma unroll
            for (int j = 0; j < 8; ++j) z[j] = (_Float16)0.f;
            Xh8[-1] = z;  // zero pad slot for masked A-frag loads
        }
        const f32x4* X4 = (const f32x4*)X;
#pragma unroll
        for (int r = 0; r < 4; ++r) {
            const int c = i0 + r * 524288;  // chunk of 8 floats
            f32x4 a = X4[2 * c];
            f32x4 b = X4[2 * c + 1];
            f16x8 o;
#pragma unroll
            for (int j = 0; j < 4; ++j) {
                o[j] = (_Float16)a[j];
                o[4 + j] = (_Float16)b[j];
            }
            Xh8[c] = o;
        }
    }
}

// ---------------------------------------------------------------------------
// cond_conv_f16: implicit-GEMM conv, software-pipelined, B-frags in VGPRs.
// Grid 1024 = 32 b x 32 rowgroups, 4 waves; wave = one full row, 8 tiles of
// 16 px. Per tile: 9 A-frag loads (16B), 18 MFMA, 8 stores. The 18 B-frags
// (tile-invariant) are hoisted to registers after one LDS staging pass.
// launch_bounds(256,4): cap 128 VGPR so 4 blocks/CU co-reside (grid = 4/CU).
// ---------------------------------------------------------------------------
__device__ __forceinline__ void load_tile(const f16x8* __restrict__ Xh8, int b,
                                          int h, int w0, int quad, int m16,
                                          f16x8 buf[9]) {
#pragma unroll
    for (int kc = 0; kc < 9; ++kc) {
        const int kh = kc / 3, kw = kc % 3;
        const int hh = h + kh - 1;         // wave-uniform
        const int ww = w0 + m16 + kw - 1;  // per-lane
        const bool ok = (hh >= 0) & (hh < HDIM) & (ww >= 0) & (ww < WDIM);
        int idx = ((b * HDIM + hh) * WDIM + ww) * 4 + quad;  // 16B units
        idx = ok ? idx : -1;  // -1 -> zeroed pad slot (no VALU consumer)
        buf[kc] = Xh8[idx];
    }
}

__global__ __launch_bounds__(256, 4) void cond_conv_f16(const f16x8* __restrict__ Xh8,
                                                        const unsigned short* __restrict__ WB,
                                                        float* __restrict__ Y) {
    __shared__ unsigned short WBl[KCOLS];  // 18432 B
    const int tid = threadIdx.x;
    const int b = blockIdx.x >> 5;
    const int hg = blockIdx.x & 31;

    // stage the per-image fragment table (16B chunks, coalesced)
    {
        const uint4* src = (const uint4*)(WB + (size_t)b * KCOLS);
        uint4* dst = (uint4*)WBl;
        for (int i = tid; i < KCOLS / 8; i += 256) dst[i] = src[i];
    }
    __syncthreads();

    const int wave = tid >> 6;
    const int lane = tid & 63;
    const int h = hg * 4 + wave;
    const int quad = lane >> 4;
    const int m16 = lane & 15;

    // Hoist all 18 B-fragments to registers (72 VGPR); tile-invariant.
    f16x8 bfrag[18];
#pragma unroll
    for (int i = 0; i < 18; ++i) {
        bfrag[i] = *(const f16x8*)(WBl + (i * 64 + lane) * 8);
    }

    f16x8 cur[9], nxt[9];
    load_tile(Xh8, b, h, 0, quad, m16, cur);

#pragma unroll
    for (int t = 0; t < 8; ++t) {
        if (t < 7) load_tile(Xh8, b, h, (t + 1) * 16, quad, m16, nxt);

        f32x4 acc0 = {0.f, 0.f, 0.f, 0.f};
        f32x4 acc1 = {0.f, 0.f, 0.f, 0.f};
#pragma unroll
        for (int kc = 0; kc < 9; ++kc) {
            acc0 = __builtin_amdgcn_mfma_f32_16x16x32_f16(cur[kc], bfrag[kc * 2], acc0, 0, 0, 0);
            acc1 = __builtin_amdgcn_mfma_f32_16x16x32_f16(cur[kc], bfrag[kc * 2 + 1], acc1, 0, 0, 0);
        }

        // D layout: col = lane&15 (co), row = quad*4 + r (pixel). Plain stores:
        // acc0+acc1 halves of each 128B line merge in L2 (nt stores gave 94MB
        // WRITE vs 66 ideal).
        float* yp = Y + (((size_t)(b * HDIM + h) * WDIM) + t * 16 + quad * 4) * COUT + m16;
#pragma unroll
        for (int r = 0; r < 4; ++r) {
            yp[r * COUT] = acc0[r];
            yp[r * COUT + 16] = acc1[r];
        }

#pragma unroll
        for (int kc = 0; kc < 9; ++kc) cur[kc] = nxt[kc];  // renamed by unroll
    }
}

// ---------------------------------------------------------------------------
// Fallback (R4 path) if ws too small for Xh: f32 X, cvt in-kernel.
// ---------------------------------------------------------------------------
__global__ __launch_bounds__(256, 4) void cond_conv_f32(const float* __restrict__ X,
                                                        const unsigned short* __restrict__ WB,
                                                        float* __restrict__ Y) {
    __shared__ unsigned short WBl[KCOLS];
    const int tid = threadIdx.x;
    const int b = blockIdx.x >> 5;
    const int hg = blockIdx.x & 31;
    {
        const uint4* src = (const uint4*)(WB + (size_t)b * KCOLS);
        uint4* dst = (uint4*)WBl;
        for (int i = tid; i < KCOLS / 8; i += 256) dst[i] = src[i];
    }
    __syncthreads();

    const int wave = tid >> 6;
    const int lane = tid & 63;
    const int h = hg * 4 + wave;
    const int quad = lane >> 4;
    const int m16 = lane & 15;
    const f32x4* X4 = (const f32x4*)X;

#pragma unroll 2
    for (int t = 0; t < 8; ++t) {
        const int w0 = t * 16;
        f32x4 acc0 = {0.f, 0.f, 0.f, 0.f};
        f32x4 acc1 = {0.f, 0.f, 0.f, 0.f};
#pragma unroll
        for (int kc = 0; kc < 9; ++kc) {
            const int kh = kc / 3, kw = kc % 3;
            const int hh = h + kh - 1;
            const int ww = w0 + m16 + kw - 1;
            const bool ok = (hh >= 0) & (hh < HDIM) & (ww >= 0) & (ww < WDIM);
            int idx = ((b * HDIM + hh) * WDIM + ww) * 8 + quad * 2;
            idx = ok ? idx : 0;
            f32x4 lo = X4[idx];
            f32x4 hi = X4[idx + 1];
            if (!ok) { lo = (f32x4)(0.f); hi = (f32x4)(0.f); }
            f16x8 a;
#pragma unroll
            for (int j = 0; j < 4; ++j) {
                a[j] = (_Float16)lo[j];
                a[4 + j] = (_Float16)hi[j];
            }
            const f16x8 bf0 = *(const f16x8*)(WBl + ((kc * 2 + 0) * 64 + lane) * 8);
            const f16x8 bf1 = *(const f16x8*)(WBl + ((kc * 2 + 1) * 64 + lane) * 8);
            acc0 = __builtin_amdgcn_mfma_f32_16x16x32_f16(a, bf0, acc0, 0, 0, 0);
            acc1 = __builtin_amdgcn_mfma_f32_16x16x32_f16(a, bf1, acc1, 0, 0, 0);
        }
        float* yp = Y + (((size_t)(b * HDIM + h) * WDIM) + w0 + quad * 4) * COUT + m16;
#pragma unroll
        for (int r = 0; r < 4; ++r) {
            yp[r * COUT] = acc0[r];
            yp[r * COUT + 16] = acc1[r];
        }
    }
}

extern "C" void kernel_launch(void* const* d_in, const int* in_sizes, int n_in,
                              void* d_out, int out_size, void* d_ws, size_t ws_size,
                              hipStream_t stream) {
    const float* X = (const float*)d_in[0];   // [32,128,128,32]
    const float* P = (const float*)d_in[1];   // [32,128]
    const float* Dw = (const float*)d_in[2];  // [128,9216]
    float* Y = (float*)d_out;                 // [32,128,128,32]

    // ws layout: [WB: 589824 B][pad: 64 B, last 16 zeroed][Xh: 33.5 MB]
    unsigned short* WB = (unsigned short*)d_ws;
    const size_t need = (size_t)589824 + 64 + (size_t)XELEMS * 2;

    if (ws_size >= need) {
        f16x8* Xh8 = (f16x8*)((char*)d_ws + 589824 + 64);
        hipLaunchKernelGGL(prep_fused, dim3(1152 + 2048), dim3(256), 0, stream,
                           P, Dw, X, WB, Xh8);
        hipLaunchKernelGGL(cond_conv_f16, dim3(1024), dim3(256), 0, stream,
                           (const f16x8*)Xh8, WB, Y);
    } else {
        hipLaunchKernelGGL(prep_fused, dim3(1152), dim3(256), 0, stream,
                           P, Dw, X, WB, (f16x8*)nullptr);
        hipLaunchKernelGGL(cond_conv_f32, dim3(1024), dim3(256), 0, stream, X, WB, Y);
    }
}